// Round 9
// baseline (1241.215 us; speedup 1.0000x reference)
//
#include <hip/hip_runtime.h>
#include <hip/hip_bf16.h>
#include <math.h>

// dims
#define MMX 64
#define NNX 128
#define DDX 64
#define RDX 128
#define TTX 96
#define LLX 512
#define PROWS 67    // padded rows: m in [-1, 65]
#define PCOLS 130   // padded cols: n in [-1, 128]

typedef short bfx8 __attribute__((ext_vector_type(8)));
typedef float floatx4 __attribute__((ext_vector_type(4)));

__device__ __forceinline__ float gelu(float v) {
  return 0.5f * v * (1.0f + erff(v * 0.70710678118654752f));
}

// ---------------------------------------------------------------------------
// prep: conv weight fp32 [CO][CI][4][3] -> bf16 [dd=dm*3+dn][co][ci]
// ---------------------------------------------------------------------------
__global__ __launch_bounds__(256) void castw_kernel(
    const float* __restrict__ w, __hip_bfloat16* __restrict__ o, int CO, int CI) {
  int i = blockIdx.x * 256 + threadIdx.x;      // CO*CI*12 total
  int ci = i % CI;
  int t = i / CI;
  int co = t % CO;
  int dd = t / CO;
  o[i] = __float2bfloat16(w[(size_t)(co * CI + ci) * 12 + dd]);
}

// ---------------------------------------------------------------------------
// prep: head weight fp32 [96][f=d*128+n] -> bf16 [96][fh=n*64+d]
// ---------------------------------------------------------------------------
__global__ __launch_bounds__(256) void headw_kernel(
    const float* __restrict__ hw, __hip_bfloat16* __restrict__ o) {
  int i = blockIdx.x * 256 + threadIdx.x;      // 96*8192 total
  int fh = i & 8191;
  int t = i >> 13;
  int d = fh & 63;
  int n = fh >> 6;
  o[i] = __float2bfloat16(hw[(size_t)t * 8192 + d * 128 + n]);
}

// ---------------------------------------------------------------------------
// embed: x [B*M, L] fp32 -> X [Bc*M, N, D] fp32 (k=8 stride=4, edge-pad right)
// ---------------------------------------------------------------------------
__global__ __launch_bounds__(256) void embed_kernel(
    const float* __restrict__ x, const float* __restrict__ w,
    const float* __restrict__ bias, float* __restrict__ xe, int bm_off) {
  int tid = blockIdx.x * 256 + threadIdx.x;
  int d  = tid & 63;
  int n  = (tid >> 6) & 127;
  int bm = tid >> 13;
  const float* xr = x + (size_t)(bm_off + bm) * LLX;
  float acc = bias[d];
  int base = n * 4;
#pragma unroll
  for (int p = 0; p < 8; ++p) {
    int i = base + p;
    if (i > LLX - 1) i = LLX - 1;
    acc += w[d * 8 + p] * xr[i];
  }
  xe[tid] = acc;
}

// ---------------------------------------------------------------------------
// depthwise conv over M (k=4, zero-pad 1/2): X fp32 [b,m,n,d] -> Yp bf16 padded
// Yp layout [b][PROWS][PCOLS][64], interior at [m+1][n+1]; halos pre-zeroed.
// ---------------------------------------------------------------------------
__global__ __launch_bounds__(256) void dw_kernel(
    const float* __restrict__ xe, const float* __restrict__ w,
    const float* __restrict__ bias, __hip_bfloat16* __restrict__ yp) {
  int tid = blockIdx.x * 256 + threadIdx.x;
  int d = tid & 63;
  int n = (tid >> 6) & 127;
  int m = (tid >> 13) & 63;
  int b = tid >> 19;
  int c = n * DDX + d;
  float acc = bias[c];
#pragma unroll
  for (int k = 0; k < 4; ++k) {
    int mm2 = m - 1 + k;
    if (mm2 >= 0 && mm2 < MMX)
      acc += w[c * 4 + k] * xe[((size_t)(b * MMX + mm2) * NNX + n) * DDX + d];
  }
  yp[(((size_t)b * PROWS + m + 1) * PCOLS + n + 1) * DDX + d] = __float2bfloat16(acc);
}

// ---------------------------------------------------------------------------
// MFMA conv2d 4x3, slim pipelined tiles:
// block = (b, m, nh): 64 px x COUT. Waves: (w>>1)=px half (32), (w&1)=co half.
// - A-row register prefetch across dm (loads in flight through the K-loop)
// - B fragments double-buffered in regs, one flattened (dn,kc) step ahead
// GELU: write Hp padded interior (bf16). else: X += resid (fp32) and Xb bf16.
// ---------------------------------------------------------------------------
template <int CIN, int COUT, bool GELU>
__global__ __launch_bounds__(256) void conv_slim(
    const __hip_bfloat16* __restrict__ in,   // padded [b][67][130][CIN]
    const __hip_bfloat16* __restrict__ wT,   // [12][COUT][CIN]
    const float* __restrict__ bias,
    __hip_bfloat16* __restrict__ hout,       // padded [b][67][130][COUT]
    float* xio,                              // [b][64][128][COUT] fp32
    __hip_bfloat16* __restrict__ xb) {       // [b][64][128][COUT] bf16
  constexpr int ASTR = CIN + 8;              // LDS stage row stride (shorts)
  constexpr int KC = CIN / 32;
  constexpr int CT = COUT / 32;              // 16-co tiles per wave (co half)
  constexpr int PT = 2;                      // 16-px tiles per wave (px half=32)
  constexpr int NS = 3 * KC;                 // flattened (dn,kc) steps per dm
  constexpr int IV = CIN / 8;                // uint4 per staged col
  constexpr int TOTCH = 66 * IV;             // staging chunks per dm
  constexpr int PAN = (TOTCH + 255) / 256;   // chunks per thread
  constexpr int EPI_SH = GELU ? 64 * (COUT + 8) : 64 * (COUT + 4) * 2;
  constexpr int SMEM_SH = (66 * ASTR > EPI_SH) ? 66 * ASTR : EPI_SH;
  __shared__ short smem[SMEM_SH];            // conv1 17.4 KB, conv2 18.0 KB

  const int i0 = blockIdx.x & 63;
  const int nh = blockIdx.x >> 6;
  const int m = ((i0 & 7) << 3) | (i0 >> 3); // XCD-locality swizzle
  const int b = blockIdx.y;
  const int n0 = nh * 64;

  const int tid = threadIdx.x;
  const int lane = tid & 63;
  const int w = tid >> 6;
  const int wp0 = (w >> 1) * 32;
  const int wc0 = (w & 1) * (COUT / 2);
  const int l15 = lane & 15;
  const int quad = lane >> 4;

  floatx4 acc[PT][CT];
#pragma unroll
  for (int i = 0; i < PT; ++i)
#pragma unroll
    for (int j = 0; j < CT; ++j) acc[i][j] = (floatx4)0.f;

  // prologue: prefetch dm=0 staging window into registers
  uint4 pa[PAN];
  {
    const uint4* src = (const uint4*)(
        in + ((size_t)b * PROWS + m) * PCOLS * CIN) + n0 * IV;
#pragma unroll
    for (int k = 0; k < PAN; ++k) {
      int idx = tid + k * 256;
      if (idx < TOTCH) pa[k] = src[idx];
    }
  }

#pragma unroll 1
  for (int dm = 0; dm < 4; ++dm) {
    __syncthreads();  // prior K-loop smem reads done
#pragma unroll
    for (int k = 0; k < PAN; ++k) {
      int idx = tid + k * 256;
      if (idx < TOTCH) {
        int col = idx / IV, cg = idx % IV;
        *(uint4*)&smem[col * ASTR + cg * 8] = pa[k];
      }
    }
    __syncthreads();
    if (dm < 3) {  // prefetch next dm's window; stays in flight during K-loop
      const uint4* src = (const uint4*)(
          in + ((size_t)b * PROWS + m + dm + 1) * PCOLS * CIN) + n0 * IV;
#pragma unroll
      for (int k = 0; k < PAN; ++k) {
        int idx = tid + k * 256;
        if (idx < TOTCH) pa[k] = src[idx];
      }
    }

    // K-loop: flattened (dn,kc), B double-buffered one step ahead
    const __hip_bfloat16* wdm = wT + (size_t)dm * 3 * COUT * CIN;
    bfx8 Bv[2][CT];
#pragma unroll
    for (int j = 0; j < CT; ++j)
      Bv[0][j] = *(const bfx8*)(
          wdm + (size_t)(wc0 + 16 * j + l15) * CIN + quad * 8);
#pragma unroll
    for (int s = 0; s < NS; ++s) {
      const int cur = s & 1;
      if (s + 1 < NS) {
        const int dn1 = (s + 1) / KC, kc1 = (s + 1) % KC;
#pragma unroll
        for (int j = 0; j < CT; ++j)
          Bv[cur ^ 1][j] = *(const bfx8*)(
              wdm + ((size_t)dn1 * COUT + wc0 + 16 * j + l15) * CIN +
              kc1 * 32 + quad * 8);
      }
      const int dn = s / KC, kc = s % KC;
      const int kb = kc * 32 + quad * 8;
      bfx8 a[PT];
#pragma unroll
      for (int i = 0; i < PT; ++i)
        a[i] = *(const bfx8*)&smem[(wp0 + 16 * i + l15 + dn) * ASTR + kb];
#pragma unroll
      for (int j = 0; j < CT; ++j)
#pragma unroll
        for (int i = 0; i < PT; ++i)
          acc[i][j] = __builtin_amdgcn_mfma_f32_16x16x32_bf16(
              a[i], Bv[cur][j], acc[i][j], 0, 0, 0);
    }
  }

  float bs[CT];
#pragma unroll
  for (int j = 0; j < CT; ++j) bs[j] = bias[wc0 + 16 * j + l15];

  // epilogue: LDS transpose (each wave writes its own px x co region),
  // then coalesced wide stores of the contiguous 64 px x COUT span.
  __syncthreads();
  if (GELU) {
    constexpr int STR2 = COUT + 8;
    short* t2 = smem;
#pragma unroll
    for (int j = 0; j < CT; ++j)
#pragma unroll
      for (int ii = 0; ii < PT; ++ii)
#pragma unroll
        for (int r = 0; r < 4; ++r) {
          int pl = wp0 + 16 * ii + quad * 4 + r;
          __hip_bfloat16 bv = __float2bfloat16(gelu(acc[ii][j][r] + bs[j]));
          t2[pl * STR2 + wc0 + 16 * j + l15] = *(short*)&bv;
        }
    __syncthreads();
    constexpr int CHUNKS = 64 * COUT / 8;
    size_t gbase = (((size_t)b * PROWS + m + 1) * PCOLS + 1 + n0) * COUT;
    for (int idx = tid; idx < CHUNKS; idx += 256) {
      int px = idx / (COUT / 8), cg = idx % (COUT / 8);
      *(uint4*)(hout + gbase + (size_t)px * COUT + cg * 8) =
          *(uint4*)&t2[px * STR2 + cg * 8];
    }
  } else {
    constexpr int STRF = COUT + 4;
    float* tf = (float*)smem;
#pragma unroll
    for (int j = 0; j < CT; ++j)
#pragma unroll
      for (int ii = 0; ii < PT; ++ii)
#pragma unroll
        for (int r = 0; r < 4; ++r) {
          int pl = wp0 + 16 * ii + quad * 4 + r;
          tf[pl * STRF + wc0 + 16 * j + l15] = acc[ii][j][r] + bs[j];
        }
    __syncthreads();
    constexpr int CHUNKS = 64 * COUT / 4;
    size_t gbase = (((size_t)b * MMX + m) * NNX + n0) * COUT;
    for (int idx = tid; idx < CHUNKS; idx += 256) {
      int px = idx / (COUT / 4), cg = idx % (COUT / 4);
      float4 a4 = *(float4*)&tf[px * STRF + cg * 4];
      size_t gx = gbase + (size_t)px * COUT + cg * 4;
      float4 xv = *(float4*)(xio + gx);
      float4 rr = make_float4(a4.x + xv.x, a4.y + xv.y, a4.z + xv.z, a4.w + xv.w);
      *(float4*)(xio + gx) = rr;
      __hip_bfloat16 o0 = __float2bfloat16(rr.x), o1 = __float2bfloat16(rr.y);
      __hip_bfloat16 o2 = __float2bfloat16(rr.z), o3 = __float2bfloat16(rr.w);
      ushort4 ov = make_ushort4(*(unsigned short*)&o0, *(unsigned short*)&o1,
                                *(unsigned short*)&o2, *(unsigned short*)&o3);
      *(ushort4*)(xb + gx) = ov;
    }
  }
}

// ---------------------------------------------------------------------------
// head split-K: P[ks][bm][t] = sum_{k in slice} Xb[bm][k] * hwT[t][k]
// grid = Bc * 8; block = 64 bm x 96 t x K=1024. 4 waves = 16 bm each.
// ---------------------------------------------------------------------------
__global__ __launch_bounds__(256) void head_split(
    const __hip_bfloat16* __restrict__ xb,   // [nbm][8192]
    const __hip_bfloat16* __restrict__ hwT,  // [96][8192]
    float* __restrict__ P, int nbm) {        // [8][nbm][96]
  const int ks = blockIdx.x & 7;
  const int bm0 = (blockIdx.x >> 3) * 64;
  const int lane = threadIdx.x & 63;
  const int w = threadIdx.x >> 6;
  const int l15 = lane & 15;
  const int quad = lane >> 4;
  const int bmw = bm0 + w * 16;

  floatx4 acc[6];
#pragma unroll
  for (int j = 0; j < 6; ++j) acc[j] = (floatx4)0.f;

  const int k0 = ks * 1024;
  const __hip_bfloat16* abase = xb + (size_t)(bmw + l15) * 8192 + k0;
  const __hip_bfloat16* bbase = hwT + (size_t)l15 * 8192 + k0;
#pragma unroll 4
  for (int kc = 0; kc < 32; ++kc) {
    const int kb = kc * 32 + quad * 8;
    bfx8 a = *(const bfx8*)(abase + kb);
#pragma unroll
    for (int j = 0; j < 6; ++j) {
      bfx8 bv = *(const bfx8*)(bbase + (size_t)(16 * j) * 8192 + kb);
      acc[j] = __builtin_amdgcn_mfma_f32_16x16x32_bf16(a, bv, acc[j], 0, 0, 0);
    }
  }
#pragma unroll
  for (int j = 0; j < 6; ++j) {
    int t = 16 * j + l15;
#pragma unroll
    for (int r = 0; r < 4; ++r) {
      int bm = bmw + quad * 4 + r;
      P[((size_t)ks * nbm + bm) * TTX + t] = acc[j][r];
    }
  }
}

__global__ __launch_bounds__(256) void head_reduce(
    const float* __restrict__ P, const float* __restrict__ hb,
    float* __restrict__ out, int nbm, int bm_off) {
  int i = blockIdx.x * 256 + threadIdx.x;    // nbm*96
  int t = i % TTX;
  int bm = i / TTX;
  float s = hb[t];
#pragma unroll
  for (int ks = 0; ks < 8; ++ks) s += P[((size_t)ks * nbm + bm) * TTX + t];
  out[(size_t)(bm_off + bm) * TTX + t] = s;
}

// ---------------------------------------------------------------------------
extern "C" void kernel_launch(void* const* d_in, const int* in_sizes, int n_in,
                              void* d_out, int out_size, void* d_ws, size_t ws_size,
                              hipStream_t stream) {
  const float* x      = (const float*)d_in[0];
  const float* emb_w  = (const float*)d_in[1];
  const float* emb_b  = (const float*)d_in[2];
  const float* head_w = (const float*)d_in[3];
  const float* head_b = (const float*)d_in[4];
  const float* dw_w1  = (const float*)d_in[5];
  const float* dw_b1  = (const float*)d_in[6];
  const float* f11_w  = (const float*)d_in[7];
  const float* f11_b  = (const float*)d_in[8];
  const float* f12_w  = (const float*)d_in[9];
  const float* f12_b  = (const float*)d_in[10];
  const float* dw_w2  = (const float*)d_in[11];
  const float* dw_b2  = (const float*)d_in[12];
  const float* f21_w  = (const float*)d_in[13];
  const float* f21_b  = (const float*)d_in[14];
  const float* f22_w  = (const float*)d_in[15];
  const float* f22_b  = (const float*)d_in[16];

  // fixed: 4 conv wT (98304 bf16 each) + hwT (786432 bf16)
  const size_t WEL = 98304, HWEL = 786432;
  __hip_bfloat16* wt11 = (__hip_bfloat16*)d_ws;
  __hip_bfloat16* wt12 = wt11 + WEL;
  __hip_bfloat16* wt21 = wt12 + WEL;
  __hip_bfloat16* wt22 = wt21 + WEL;
  __hip_bfloat16* hwT  = wt22 + WEL;
  char* dyn = (char*)(hwT + HWEL);
  const size_t fixed_bytes = (4 * WEL + HWEL) * 2;

  const size_t YP_B = (size_t)PROWS * PCOLS * DDX * 2;    // 1,114,880
  const size_t HP_B = (size_t)PROWS * PCOLS * RDX * 2;    // 2,229,760
  const size_t X_B  = (size_t)MMX * NNX * DDX * 4;        // 2,097,152
  const size_t XB_B = (size_t)MMX * NNX * DDX * 2;        // 1,048,576
  const size_t P_B  = (size_t)8 * MMX * TTX * 4;          //   196,608
  const size_t PER_B = YP_B + HP_B + X_B + XB_B + P_B;
  int Bc = 32;
  while (Bc > 1 && fixed_bytes + (size_t)Bc * PER_B > ws_size) Bc >>= 1;

  __hip_bfloat16* Yp = (__hip_bfloat16*)dyn;
  __hip_bfloat16* Hp = (__hip_bfloat16*)(dyn + (size_t)Bc * YP_B);
  float* X  = (float*)(dyn + (size_t)Bc * (YP_B + HP_B));
  __hip_bfloat16* Xb = (__hip_bfloat16*)(dyn + (size_t)Bc * (YP_B + HP_B + X_B));
  float* P  = (float*)(dyn + (size_t)Bc * (YP_B + HP_B + X_B + XB_B));
  const int nbm = Bc * MMX;

  // prep (once per launch)
  castw_kernel<<<384, 256, 0, stream>>>(f11_w, wt11, RDX, DDX);
  castw_kernel<<<384, 256, 0, stream>>>(f12_w, wt12, DDX, RDX);
  castw_kernel<<<384, 256, 0, stream>>>(f21_w, wt21, RDX, DDX);
  castw_kernel<<<384, 256, 0, stream>>>(f22_w, wt22, DDX, RDX);
  headw_kernel<<<3072, 256, 0, stream>>>(head_w, hwT);
  // zero padded halo buffers (ws is re-poisoned before every timed launch)
  hipMemsetAsync(Yp, 0, (size_t)Bc * (YP_B + HP_B), stream);

  for (int b0 = 0; b0 < 32; b0 += Bc) {
    int bm_off = b0 * MMX;
    embed_kernel<<<Bc * 2048, 256, 0, stream>>>(x, emb_w, emb_b, X, bm_off);

    for (int l = 0; l < 2; ++l) {
      const float* dwW = l ? dw_w2 : dw_w1;
      const float* dwB = l ? dw_b2 : dw_b1;
      const __hip_bfloat16* w1 = l ? wt21 : wt11;
      const float* b1 = l ? f21_b : f11_b;
      const __hip_bfloat16* w2 = l ? wt22 : wt12;
      const float* b2 = l ? f22_b : f12_b;

      dw_kernel<<<Bc * 2048, 256, 0, stream>>>(X, dwW, dwB, Yp);
      conv_slim<DDX, RDX, true>
          <<<dim3(128, Bc), 256, 0, stream>>>(Yp, w1, b1, Hp, nullptr, nullptr);
      conv_slim<RDX, DDX, false>
          <<<dim3(128, Bc), 256, 0, stream>>>(Hp, w2, b2, nullptr, X, Xb);
    }

    head_split<<<Bc * 8, 256, 0, stream>>>(Xb, hwT, P, nbm);
    head_reduce<<<Bc * 24, 256, 0, stream>>>(P, head_b, (float*)d_out, nbm, bm_off);
  }
}

// Round 10
// 1063.915 us; speedup vs baseline: 1.1666x; 1.1666x over previous
//
#include <hip/hip_runtime.h>
#include <hip/hip_bf16.h>
#include <math.h>

// dims
#define MMX 64
#define NNX 128
#define DDX 64
#define RDX 128
#define TTX 96
#define LLX 512
#define PROWS 67    // padded rows: m in [-1, 65]
#define PCOLS 130   // padded cols: n in [-1, 128]

typedef short bfx8 __attribute__((ext_vector_type(8)));
typedef float floatx4 __attribute__((ext_vector_type(4)));

__device__ __forceinline__ float gelu(float v) {
  return 0.5f * v * (1.0f + erff(v * 0.70710678118654752f));
}

// ---------------------------------------------------------------------------
// prep: conv weight fp32 [CO][CI][4][3] -> bf16 [dd=dm*3+dn][co][ci]
// ---------------------------------------------------------------------------
__global__ __launch_bounds__(256) void castw_kernel(
    const float* __restrict__ w, __hip_bfloat16* __restrict__ o, int CO, int CI) {
  int i = blockIdx.x * 256 + threadIdx.x;      // CO*CI*12 total
  int ci = i % CI;
  int t = i / CI;
  int co = t % CO;
  int dd = t / CO;
  o[i] = __float2bfloat16(w[(size_t)(co * CI + ci) * 12 + dd]);
}

// ---------------------------------------------------------------------------
// prep: head weight fp32 [96][f=d*128+n] -> bf16 [96][fh=n*64+d]
// ---------------------------------------------------------------------------
__global__ __launch_bounds__(256) void headw_kernel(
    const float* __restrict__ hw, __hip_bfloat16* __restrict__ o) {
  int i = blockIdx.x * 256 + threadIdx.x;      // 96*8192 total
  int fh = i & 8191;
  int t = i >> 13;
  int d = fh & 63;
  int n = fh >> 6;
  o[i] = __float2bfloat16(hw[(size_t)t * 8192 + d * 128 + n]);
}

// ---------------------------------------------------------------------------
// halo zero: clear pad frame of a [32][PROWS][PCOLS][C] bf16 buffer.
// per b: rows {0,65,66} all 130 cols (390 slots) + rows 1..64 cols {0,129}
// (128 slots) = 518 col-slots x C channels.
// ---------------------------------------------------------------------------
__global__ __launch_bounds__(256) void halo_zero(
    __hip_bfloat16* __restrict__ p, int C) {
  int i = blockIdx.x * 256 + threadIdx.x;
  int per_b = 518 * C;
  int b = i / per_b;
  if (b >= 32) return;
  int r = i % per_b;
  int slot = r / C, ch = r % C;
  int row, col;
  if (slot < 390) {
    int rr = slot / 130;
    row = (rr == 0) ? 0 : (64 + rr);          // 0, 65, 66
    col = slot % 130;
  } else {
    int s2 = slot - 390;
    row = 1 + (s2 >> 1);
    col = (s2 & 1) ? 129 : 0;
  }
  p[(((size_t)b * PROWS + row) * PCOLS + col) * C + ch] = __float2bfloat16(0.f);
}

// ---------------------------------------------------------------------------
// embed: x [B*M, L] fp32 -> X [Bc*M, N, D] fp32 (k=8 stride=4, edge-pad right)
// ---------------------------------------------------------------------------
__global__ __launch_bounds__(256) void embed_kernel(
    const float* __restrict__ x, const float* __restrict__ w,
    const float* __restrict__ bias, float* __restrict__ xe, int bm_off) {
  int tid = blockIdx.x * 256 + threadIdx.x;
  int d  = tid & 63;
  int n  = (tid >> 6) & 127;
  int bm = tid >> 13;
  const float* xr = x + (size_t)(bm_off + bm) * LLX;
  float acc = bias[d];
  int base = n * 4;
#pragma unroll
  for (int p = 0; p < 8; ++p) {
    int i = base + p;
    if (i > LLX - 1) i = LLX - 1;
    acc += w[d * 8 + p] * xr[i];
  }
  xe[tid] = acc;
}

// ---------------------------------------------------------------------------
// depthwise conv over M (k=4, zero-pad 1/2): X fp32 [b,m,n,d] -> Yp bf16 padded
// ---------------------------------------------------------------------------
__global__ __launch_bounds__(256) void dw_kernel(
    const float* __restrict__ xe, const float* __restrict__ w,
    const float* __restrict__ bias, __hip_bfloat16* __restrict__ yp) {
  int tid = blockIdx.x * 256 + threadIdx.x;
  int d = tid & 63;
  int n = (tid >> 6) & 127;
  int m = (tid >> 13) & 63;
  int b = tid >> 19;
  int c = n * DDX + d;
  float acc = bias[c];
#pragma unroll
  for (int k = 0; k < 4; ++k) {
    int mm2 = m - 1 + k;
    if (mm2 >= 0 && mm2 < MMX)
      acc += w[c * 4 + k] * xe[((size_t)(b * MMX + mm2) * NNX + n) * DDX + d];
  }
  yp[(((size_t)b * PROWS + m + 1) * PCOLS + n + 1) * DDX + d] = __float2bfloat16(acc);
}

// ---------------------------------------------------------------------------
// MFMA conv2d 4x3. Block = one (b,m): 128 px x COUT.
// Waves: (w>>1)=px half (64 px, PT=4), (w&1)=co half (CT tiles).
// Per dm: ALL B fragments (3 dn x KC x CT) loaded into regs BEFORE the staging
// barrier (in flight across it); A row staged to LDS from register prefetch
// pa[] requested during the previous dm's K-loop. __launch_bounds__(256,2)
// pins the VGPR budget at 256 -> no scratch spill (R9's failure mode).
// GELU: write Hp padded interior (bf16). else: X += resid (fp32) and Xb bf16.
// ---------------------------------------------------------------------------
template <int CIN, int COUT, bool GELU>
__global__ __launch_bounds__(256, 2) void conv_reg(
    const __hip_bfloat16* __restrict__ in,   // padded [b][67][130][CIN]
    const __hip_bfloat16* __restrict__ wT,   // [12][COUT][CIN]
    const float* __restrict__ bias,
    __hip_bfloat16* __restrict__ hout,       // padded [b][67][130][COUT]
    float* xio,                              // [b][64][128][COUT] fp32
    __hip_bfloat16* __restrict__ xb) {       // [b][64][128][COUT] bf16
  constexpr int ASTR = CIN + 8;              // LDS row stride (shorts)
  constexpr int KC = CIN / 32;
  constexpr int CT = COUT / 32;              // 16-co tiles per wave (co half)
  constexpr int PT = 4;                      // 16-px tiles per wave (px half)
  constexpr int IV = CIN / 8;                // uint4 per staged col
  constexpr int TOTCH = 130 * IV;            // staging chunks per dm
  constexpr int PAN = (TOTCH + 255) / 256;
  __shared__ short smem[130 * ASTR];         // conv1 18.7 KB, conv2 35.4 KB

  const int i0 = blockIdx.x & 63;
  const int m = ((i0 & 7) << 3) | (i0 >> 3); // XCD-locality swizzle
  const int b = blockIdx.x >> 6;
  const int tid = threadIdx.x;
  const int lane = tid & 63;
  const int w = tid >> 6;
  const int wp0 = (w >> 1) * 64;
  const int wc0 = (w & 1) * (COUT / 2);
  const int l15 = lane & 15;
  const int quad = lane >> 4;

  floatx4 acc[PT][CT];
#pragma unroll
  for (int i = 0; i < PT; ++i)
#pragma unroll
    for (int j = 0; j < CT; ++j) acc[i][j] = (floatx4)0.f;

  // prologue: prefetch dm=0 staging row into registers
  uint4 pa[PAN];
  {
    const uint4* src = (const uint4*)(in + ((size_t)b * PROWS + m) * PCOLS * CIN);
#pragma unroll
    for (int k = 0; k < PAN; ++k) {
      int idx = tid + k * 256;
      if (idx < TOTCH) pa[k] = src[idx];
    }
  }

#pragma unroll 1
  for (int dm = 0; dm < 4; ++dm) {
    // all B fragments for this dm -> regs; loads stay in flight across the
    // barrier + LDS staging and are consumed over the whole K-loop.
    bfx8 Bf[3][KC][CT];
    const __hip_bfloat16* wdm = wT + (size_t)dm * 3 * COUT * CIN;
#pragma unroll
    for (int dn = 0; dn < 3; ++dn)
#pragma unroll
      for (int kc = 0; kc < KC; ++kc)
#pragma unroll
        for (int j = 0; j < CT; ++j)
          Bf[dn][kc][j] = *(const bfx8*)(
              wdm + ((size_t)dn * COUT + wc0 + 16 * j + l15) * CIN +
              kc * 32 + quad * 8);

    __syncthreads();  // prior K-loop smem reads done before restage
#pragma unroll
    for (int k = 0; k < PAN; ++k) {
      int idx = tid + k * 256;
      if (idx < TOTCH) {
        int col = idx / IV, cg = idx % IV;
        *(uint4*)&smem[col * ASTR + cg * 8] = pa[k];
      }
    }
    __syncthreads();

    if (dm < 3) {  // prefetch next dm's row; in flight during this K-loop
      const uint4* src = (const uint4*)(
          in + ((size_t)b * PROWS + m + dm + 1) * PCOLS * CIN);
#pragma unroll
      for (int k = 0; k < PAN; ++k) {
        int idx = tid + k * 256;
        if (idx < TOTCH) pa[k] = src[idx];
      }
    }

#pragma unroll
    for (int dn = 0; dn < 3; ++dn) {
#pragma unroll
      for (int kc = 0; kc < KC; ++kc) {
        const int kb = kc * 32 + quad * 8;
        bfx8 a[PT];
#pragma unroll
        for (int i = 0; i < PT; ++i)
          a[i] = *(const bfx8*)&smem[(wp0 + 16 * i + l15 + dn) * ASTR + kb];
#pragma unroll
        for (int j = 0; j < CT; ++j)
#pragma unroll
          for (int i = 0; i < PT; ++i)
            acc[i][j] = __builtin_amdgcn_mfma_f32_16x16x32_bf16(
                a[i], Bf[dn][kc][j], acc[i][j], 0, 0, 0);
      }
    }
  }

  float bs[CT];
#pragma unroll
  for (int j = 0; j < CT; ++j) bs[j] = bias[wc0 + 16 * j + l15];

  // epilogue: per px-half LDS transpose -> coalesced wide stores
  __syncthreads();
#pragma unroll 1
  for (int h = 0; h < 2; ++h) {
    if (GELU) {
      constexpr int STR2 = COUT + 8;
      short* t2 = smem;
      if ((w >> 1) == h) {
#pragma unroll
        for (int j = 0; j < CT; ++j)
#pragma unroll
          for (int ii = 0; ii < PT; ++ii)
#pragma unroll
            for (int r = 0; r < 4; ++r) {
              int pl = 16 * ii + quad * 4 + r;   // px within this half
              __hip_bfloat16 bv = __float2bfloat16(gelu(acc[ii][j][r] + bs[j]));
              t2[pl * STR2 + wc0 + 16 * j + l15] = *(short*)&bv;
            }
      }
      __syncthreads();
      constexpr int CHUNKS = 64 * COUT / 8;
      size_t gbase = (((size_t)b * PROWS + m + 1) * PCOLS + 1 + h * 64) * COUT;
      for (int idx = tid; idx < CHUNKS; idx += 256) {
        int px = idx / (COUT / 8), cg = idx % (COUT / 8);
        *(uint4*)(hout + gbase + (size_t)px * COUT + cg * 8) =
            *(uint4*)&t2[px * STR2 + cg * 8];
      }
      __syncthreads();
    } else {
      constexpr int STRF = COUT + 4;
      float* tf = (float*)smem;
      if ((w >> 1) == h) {
#pragma unroll
        for (int j = 0; j < CT; ++j)
#pragma unroll
          for (int ii = 0; ii < PT; ++ii)
#pragma unroll
            for (int r = 0; r < 4; ++r) {
              int pl = 16 * ii + quad * 4 + r;
              tf[pl * STRF + wc0 + 16 * j + l15] = acc[ii][j][r] + bs[j];
            }
      }
      __syncthreads();
      constexpr int CHUNKS = 64 * COUT / 4;
      size_t gbase = (((size_t)b * MMX + m) * NNX + h * 64) * COUT;
      for (int idx = tid; idx < CHUNKS; idx += 256) {
        int px = idx / (COUT / 4), cg = idx % (COUT / 4);
        float4 a4 = *(float4*)&tf[px * STRF + cg * 4];
        size_t gx = gbase + (size_t)px * COUT + cg * 4;
        float4 xv = *(float4*)(xio + gx);
        float4 rr = make_float4(a4.x + xv.x, a4.y + xv.y, a4.z + xv.z, a4.w + xv.w);
        *(float4*)(xio + gx) = rr;
        __hip_bfloat16 o0 = __float2bfloat16(rr.x), o1 = __float2bfloat16(rr.y);
        __hip_bfloat16 o2 = __float2bfloat16(rr.z), o3 = __float2bfloat16(rr.w);
        ushort4 ov = make_ushort4(*(unsigned short*)&o0, *(unsigned short*)&o1,
                                  *(unsigned short*)&o2, *(unsigned short*)&o3);
        *(ushort4*)(xb + gx) = ov;
      }
      __syncthreads();
    }
  }
}

// ---------------------------------------------------------------------------
// head split-K: P[ks][bm][t] = sum_{k in slice} Xb[bm][k] * hwT[t][k]
// ---------------------------------------------------------------------------
__global__ __launch_bounds__(256) void head_split(
    const __hip_bfloat16* __restrict__ xb,   // [nbm][8192]
    const __hip_bfloat16* __restrict__ hwT,  // [96][8192]
    float* __restrict__ P, int nbm) {        // [8][nbm][96]
  const int ks = blockIdx.x & 7;
  const int bm0 = (blockIdx.x >> 3) * 64;
  const int lane = threadIdx.x & 63;
  const int w = threadIdx.x >> 6;
  const int l15 = lane & 15;
  const int quad = lane >> 4;
  const int bmw = bm0 + w * 16;

  floatx4 acc[6];
#pragma unroll
  for (int j = 0; j < 6; ++j) acc[j] = (floatx4)0.f;

  const int k0 = ks * 1024;
  const __hip_bfloat16* abase = xb + (size_t)(bmw + l15) * 8192 + k0;
  const __hip_bfloat16* bbase = hwT + (size_t)l15 * 8192 + k0;
#pragma unroll 4
  for (int kc = 0; kc < 32; ++kc) {
    const int kb = kc * 32 + quad * 8;
    bfx8 a = *(const bfx8*)(abase + kb);
#pragma unroll
    for (int j = 0; j < 6; ++j) {
      bfx8 bv = *(const bfx8*)(bbase + (size_t)(16 * j) * 8192 + kb);
      acc[j] = __builtin_amdgcn_mfma_f32_16x16x32_bf16(a, bv, acc[j], 0, 0, 0);
    }
  }
#pragma unroll
  for (int j = 0; j < 6; ++j) {
    int t = 16 * j + l15;
#pragma unroll
    for (int r = 0; r < 4; ++r) {
      int bm = bmw + quad * 4 + r;
      P[((size_t)ks * nbm + bm) * TTX + t] = acc[j][r];
    }
  }
}

__global__ __launch_bounds__(256) void head_reduce(
    const float* __restrict__ P, const float* __restrict__ hb,
    float* __restrict__ out, int nbm, int bm_off) {
  int i = blockIdx.x * 256 + threadIdx.x;    // nbm*96
  int t = i % TTX;
  int bm = i / TTX;
  float s = hb[t];
#pragma unroll
  for (int ks = 0; ks < 8; ++ks) s += P[((size_t)ks * nbm + bm) * TTX + t];
  out[(size_t)(bm_off + bm) * TTX + t] = s;
}

// ---------------------------------------------------------------------------
extern "C" void kernel_launch(void* const* d_in, const int* in_sizes, int n_in,
                              void* d_out, int out_size, void* d_ws, size_t ws_size,
                              hipStream_t stream) {
  const float* x      = (const float*)d_in[0];
  const float* emb_w  = (const float*)d_in[1];
  const float* emb_b  = (const float*)d_in[2];
  const float* head_w = (const float*)d_in[3];
  const float* head_b = (const float*)d_in[4];
  const float* dw_w1  = (const float*)d_in[5];
  const float* dw_b1  = (const float*)d_in[6];
  const float* f11_w  = (const float*)d_in[7];
  const float* f11_b  = (const float*)d_in[8];
  const float* f12_w  = (const float*)d_in[9];
  const float* f12_b  = (const float*)d_in[10];
  const float* dw_w2  = (const float*)d_in[11];
  const float* dw_b2  = (const float*)d_in[12];
  const float* f21_w  = (const float*)d_in[13];
  const float* f21_b  = (const float*)d_in[14];
  const float* f22_w  = (const float*)d_in[15];
  const float* f22_b  = (const float*)d_in[16];

  // fixed: 4 conv wT (98304 bf16 each) + hwT (786432 bf16)
  const size_t WEL = 98304, HWEL = 786432;
  __hip_bfloat16* wt11 = (__hip_bfloat16*)d_ws;
  __hip_bfloat16* wt12 = wt11 + WEL;
  __hip_bfloat16* wt21 = wt12 + WEL;
  __hip_bfloat16* wt22 = wt21 + WEL;
  __hip_bfloat16* hwT  = wt22 + WEL;
  char* dyn = (char*)(hwT + HWEL);
  const size_t fixed_bytes = (4 * WEL + HWEL) * 2;

  const size_t YP_B = (size_t)PROWS * PCOLS * DDX * 2;    // 1,114,880
  const size_t HP_B = (size_t)PROWS * PCOLS * RDX * 2;    // 2,229,760
  const size_t X_B  = (size_t)MMX * NNX * DDX * 4;        // 2,097,152
  const size_t XB_B = (size_t)MMX * NNX * DDX * 2;        // 1,048,576
  const size_t P_B  = (size_t)8 * MMX * TTX * 4;          //   196,608
  const size_t PER_B = YP_B + HP_B + X_B + XB_B + P_B;
  int Bc = 32;
  while (Bc > 1 && fixed_bytes + (size_t)Bc * PER_B > ws_size) Bc >>= 1;

  __hip_bfloat16* Yp = (__hip_bfloat16*)dyn;
  __hip_bfloat16* Hp = (__hip_bfloat16*)(dyn + (size_t)Bc * YP_B);
  float* X  = (float*)(dyn + (size_t)Bc * (YP_B + HP_B));
  __hip_bfloat16* Xb = (__hip_bfloat16*)(dyn + (size_t)Bc * (YP_B + HP_B + X_B));
  float* P  = (float*)(dyn + (size_t)Bc * (YP_B + HP_B + X_B + XB_B));
  const int nbm = Bc * MMX;

  // prep (once per launch)
  castw_kernel<<<384, 256, 0, stream>>>(f11_w, wt11, RDX, DDX);
  castw_kernel<<<384, 256, 0, stream>>>(f12_w, wt12, DDX, RDX);
  castw_kernel<<<384, 256, 0, stream>>>(f21_w, wt21, RDX, DDX);
  castw_kernel<<<384, 256, 0, stream>>>(f22_w, wt22, DDX, RDX);
  headw_kernel<<<3072, 256, 0, stream>>>(head_w, hwT);
  // zero pad frames only (interiors always rewritten before read)
  halo_zero<<<(32 * 518 * DDX + 255) / 256, 256, 0, stream>>>(Yp, DDX);
  halo_zero<<<(32 * 518 * RDX + 255) / 256, 256, 0, stream>>>(Hp, RDX);

  for (int b0 = 0; b0 < 32; b0 += Bc) {
    int bm_off = b0 * MMX;
    embed_kernel<<<Bc * 2048, 256, 0, stream>>>(x, emb_w, emb_b, X, bm_off);

    for (int l = 0; l < 2; ++l) {
      const float* dwW = l ? dw_w2 : dw_w1;
      const float* dwB = l ? dw_b2 : dw_b1;
      const __hip_bfloat16* w1 = l ? wt21 : wt11;
      const float* b1 = l ? f21_b : f11_b;
      const __hip_bfloat16* w2 = l ? wt22 : wt12;
      const float* b2 = l ? f22_b : f12_b;

      dw_kernel<<<Bc * 2048, 256, 0, stream>>>(X, dwW, dwB, Yp);
      conv_reg<DDX, RDX, true>
          <<<Bc * MMX, 256, 0, stream>>>(Yp, w1, b1, Hp, nullptr, nullptr);
      conv_reg<RDX, DDX, false>
          <<<Bc * MMX, 256, 0, stream>>>(Hp, w2, b2, nullptr, X, Xb);
    }

    head_split<<<Bc * 8, 256, 0, stream>>>(Xb, hwT, P, nbm);
    head_reduce<<<Bc * 24, 256, 0, stream>>>(P, head_b, (float*)d_out, nbm, bm_off);
  }
}

// Round 11
// 934.228 us; speedup vs baseline: 1.3286x; 1.1388x over previous
//
#include <hip/hip_runtime.h>
#include <hip/hip_bf16.h>
#include <math.h>

// dims
#define MMX 64
#define NNX 128
#define DDX 64
#define RDX 128
#define TTX 96
#define LLX 512
#define PROWS 67    // padded rows: m in [-1, 65]
#define PCOLS 130   // padded cols: n in [-1, 128]

typedef short bfx8 __attribute__((ext_vector_type(8)));
typedef float floatx4 __attribute__((ext_vector_type(4)));

__device__ __forceinline__ float gelu(float v) {
  return 0.5f * v * (1.0f + erff(v * 0.70710678118654752f));
}

// ---------------------------------------------------------------------------
// prep: conv weight fp32 [CO][CI][4][3] -> bf16 [dd=dm*3+dn][co][ci]
// ---------------------------------------------------------------------------
__global__ __launch_bounds__(256) void castw_kernel(
    const float* __restrict__ w, __hip_bfloat16* __restrict__ o, int CO, int CI) {
  int i = blockIdx.x * 256 + threadIdx.x;      // CO*CI*12 total
  int ci = i % CI;
  int t = i / CI;
  int co = t % CO;
  int dd = t / CO;
  o[i] = __float2bfloat16(w[(size_t)(co * CI + ci) * 12 + dd]);
}

// ---------------------------------------------------------------------------
// prep: head weight fp32 [96][f=d*128+n] -> bf16 [96][fh=n*64+d]
// ---------------------------------------------------------------------------
__global__ __launch_bounds__(256) void headw_kernel(
    const float* __restrict__ hw, __hip_bfloat16* __restrict__ o) {
  int i = blockIdx.x * 256 + threadIdx.x;      // 96*8192 total
  int fh = i & 8191;
  int t = i >> 13;
  int d = fh & 63;
  int n = fh >> 6;
  o[i] = __float2bfloat16(hw[(size_t)t * 8192 + d * 128 + n]);
}

// ---------------------------------------------------------------------------
// halo zero: clear pad frame of a [32][PROWS][PCOLS][C] bf16 buffer.
// ---------------------------------------------------------------------------
__global__ __launch_bounds__(256) void halo_zero(
    __hip_bfloat16* __restrict__ p, int C) {
  int i = blockIdx.x * 256 + threadIdx.x;
  int per_b = 518 * C;
  int b = i / per_b;
  if (b >= 32) return;
  int r = i % per_b;
  int slot = r / C, ch = r % C;
  int row, col;
  if (slot < 390) {
    int rr = slot / 130;
    row = (rr == 0) ? 0 : (64 + rr);          // 0, 65, 66
    col = slot % 130;
  } else {
    int s2 = slot - 390;
    row = 1 + (s2 >> 1);
    col = (s2 & 1) ? 129 : 0;
  }
  p[(((size_t)b * PROWS + row) * PCOLS + col) * C + ch] = __float2bfloat16(0.f);
}

// ---------------------------------------------------------------------------
// embed: x [B*M, L] fp32 -> X [Bc*M, N, D] fp32 (k=8 stride=4, edge-pad right)
// ---------------------------------------------------------------------------
__global__ __launch_bounds__(256) void embed_kernel(
    const float* __restrict__ x, const float* __restrict__ w,
    const float* __restrict__ bias, float* __restrict__ xe, int bm_off) {
  int tid = blockIdx.x * 256 + threadIdx.x;
  int d  = tid & 63;
  int n  = (tid >> 6) & 127;
  int bm = tid >> 13;
  const float* xr = x + (size_t)(bm_off + bm) * LLX;
  float acc = bias[d];
  int base = n * 4;
#pragma unroll
  for (int p = 0; p < 8; ++p) {
    int i = base + p;
    if (i > LLX - 1) i = LLX - 1;
    acc += w[d * 8 + p] * xr[i];
  }
  xe[tid] = acc;
}

// ---------------------------------------------------------------------------
// depthwise conv over M (k=4, zero-pad 1/2): X fp32 [b,m,n,d] -> Yp bf16 padded
// ---------------------------------------------------------------------------
__global__ __launch_bounds__(256) void dw_kernel(
    const float* __restrict__ xe, const float* __restrict__ w,
    const float* __restrict__ bias, __hip_bfloat16* __restrict__ yp) {
  int tid = blockIdx.x * 256 + threadIdx.x;
  int d = tid & 63;
  int n = (tid >> 6) & 127;
  int m = (tid >> 13) & 63;
  int b = tid >> 19;
  int c = n * DDX + d;
  float acc = bias[c];
#pragma unroll
  for (int k = 0; k < 4; ++k) {
    int mm2 = m - 1 + k;
    if (mm2 >= 0 && mm2 < MMX)
      acc += w[c * 4 + k] * xe[((size_t)(b * MMX + mm2) * NNX + n) * DDX + d];
  }
  yp[(((size_t)b * PROWS + m + 1) * PCOLS + n + 1) * DDX + d] = __float2bfloat16(acc);
}

// ---------------------------------------------------------------------------
// MFMA conv2d 4x3, software-pipelined. Block = one (b,m): 128 px x COUT.
// Waves: (w>>1)=px half (64 px, PT=4), (w&1)=co half (CT tiles).
// K flattened into NS steps over (dm,dn,kc). B fragments in a 4-deep register
// ring: step s consumes Bf[s&3], then issues the load for step s+4 into the
// freed slot -> ~300 cyc of MFMA in flight over every L2 B-load.
// amdgpu_waves_per_eu(2,2) pins 2 waves/SIMD => 256-VGPR budget, no spill
// (R8/R10 failure mode: allocator spilled chasing implicit occupancy).
// A row staged to LDS per dm from register prefetch pa[] (R10 pattern).
// GELU: write Hp padded interior (bf16). else: X += resid (fp32) and Xb bf16.
// ---------------------------------------------------------------------------
template <int CIN, int COUT, bool GELU>
__global__ void __launch_bounds__(256)
__attribute__((amdgpu_waves_per_eu(2, 2)))
conv_pipe(
    const __hip_bfloat16* __restrict__ in,   // padded [b][67][130][CIN]
    const __hip_bfloat16* __restrict__ wT,   // [12][COUT][CIN]
    const float* __restrict__ bias,
    __hip_bfloat16* __restrict__ hout,       // padded [b][67][130][COUT]
    float* xio,                              // [b][64][128][COUT] fp32
    __hip_bfloat16* __restrict__ xb) {       // [b][64][128][COUT] bf16
  constexpr int ASTR = CIN + 8;              // LDS row stride (shorts)
  constexpr int KC = CIN / 32;
  constexpr int CT = COUT / 32;              // 16-co tiles per wave (co half)
  constexpr int PT = 4;                      // 16-px tiles per wave (px half)
  constexpr int NS = 12 * KC;                // flattened (dm,dn,kc) steps
  constexpr int IV = CIN / 8;                // uint4 per staged col
  constexpr int TOTCH = 130 * IV;            // staging chunks per dm
  constexpr int PAN = (TOTCH + 255) / 256;
  __shared__ short smem[130 * ASTR];         // conv1 18.7 KB, conv2 35.4 KB

  const int i0 = blockIdx.x & 63;
  const int m = ((i0 & 7) << 3) | (i0 >> 3); // XCD-locality swizzle
  const int b = blockIdx.x >> 6;
  const int tid = threadIdx.x;
  const int lane = tid & 63;
  const int w = tid >> 6;
  const int wp0 = (w >> 1) * 64;
  const int wc0 = (w & 1) * (COUT / 2);
  const int l15 = lane & 15;
  const int quad = lane >> 4;

  floatx4 acc[PT][CT];
#pragma unroll
  for (int i = 0; i < PT; ++i)
#pragma unroll
    for (int j = 0; j < CT; ++j) acc[i][j] = (floatx4)0.f;

  // B-ring load: step s -> (dd = s/KC, kc = s%KC)
  bfx8 Bf[4][CT];
  auto loadB = [&](int s, int slot) {
    const int dd = s / KC;
    const int kc = s % KC;
    const __hip_bfloat16* wp = wT + (size_t)dd * COUT * CIN;
#pragma unroll
    for (int j = 0; j < CT; ++j)
      Bf[slot][j] = *(const bfx8*)(
          wp + (size_t)(wc0 + 16 * j + l15) * CIN + kc * 32 + quad * 8);
  };

  // prologue: pa <- row m+0; B ring <- steps 0..3
  uint4 pa[PAN];
  {
    const uint4* src = (const uint4*)(in + ((size_t)b * PROWS + m) * PCOLS * CIN);
#pragma unroll
    for (int k = 0; k < PAN; ++k) {
      int idx = tid + k * 256;
      if (idx < TOTCH) pa[k] = src[idx];
    }
  }
#pragma unroll
  for (int s = 0; s < 4; ++s) loadB(s, s);

#pragma unroll
  for (int s = 0; s < NS; ++s) {
    const int dm = s / (3 * KC);
    if (s % (3 * KC) == 0) {
      __syncthreads();  // prior dm's smem reads done before restage
#pragma unroll
      for (int k = 0; k < PAN; ++k) {
        int idx = tid + k * 256;
        if (idx < TOTCH) {
          int col = idx / IV, cg = idx % IV;
          *(uint4*)&smem[col * ASTR + cg * 8] = pa[k];
        }
      }
      __syncthreads();
      if (dm < 3) {  // prefetch next row; in flight through this dm's steps
        const uint4* src = (const uint4*)(
            in + ((size_t)b * PROWS + m + dm + 1) * PCOLS * CIN);
#pragma unroll
        for (int k = 0; k < PAN; ++k) {
          int idx = tid + k * 256;
          if (idx < TOTCH) pa[k] = src[idx];
        }
      }
    }
    const int dn = (s / KC) % 3;
    const int kc = s % KC;
    const int kb = kc * 32 + quad * 8;
    bfx8 a[PT];
#pragma unroll
    for (int i = 0; i < PT; ++i)
      a[i] = *(const bfx8*)&smem[(wp0 + 16 * i + l15 + dn) * ASTR + kb];
#pragma unroll
    for (int j = 0; j < CT; ++j)
#pragma unroll
      for (int i = 0; i < PT; ++i)
        acc[i][j] = __builtin_amdgcn_mfma_f32_16x16x32_bf16(
            a[i], Bf[s & 3][j], acc[i][j], 0, 0, 0);
    if (s + 4 < NS) loadB(s + 4, s & 3);  // refill freed slot (4-step lookahead)
  }

  float bs[CT];
#pragma unroll
  for (int j = 0; j < CT; ++j) bs[j] = bias[wc0 + 16 * j + l15];

  // epilogue: per px-half LDS transpose -> coalesced wide stores
  __syncthreads();
#pragma unroll 1
  for (int h = 0; h < 2; ++h) {
    if (GELU) {
      constexpr int STR2 = COUT + 8;
      short* t2 = smem;
      if ((w >> 1) == h) {
#pragma unroll
        for (int j = 0; j < CT; ++j)
#pragma unroll
          for (int ii = 0; ii < PT; ++ii)
#pragma unroll
            for (int r = 0; r < 4; ++r) {
              int pl = 16 * ii + quad * 4 + r;   // px within this half
              __hip_bfloat16 bv = __float2bfloat16(gelu(acc[ii][j][r] + bs[j]));
              t2[pl * STR2 + wc0 + 16 * j + l15] = *(short*)&bv;
            }
      }
      __syncthreads();
      constexpr int CHUNKS = 64 * COUT / 8;
      size_t gbase = (((size_t)b * PROWS + m + 1) * PCOLS + 1 + h * 64) * COUT;
      for (int idx = tid; idx < CHUNKS; idx += 256) {
        int px = idx / (COUT / 8), cg = idx % (COUT / 8);
        *(uint4*)(hout + gbase + (size_t)px * COUT + cg * 8) =
            *(uint4*)&t2[px * STR2 + cg * 8];
      }
      __syncthreads();
    } else {
      constexpr int STRF = COUT + 4;
      float* tf = (float*)smem;
      if ((w >> 1) == h) {
#pragma unroll
        for (int j = 0; j < CT; ++j)
#pragma unroll
          for (int ii = 0; ii < PT; ++ii)
#pragma unroll
            for (int r = 0; r < 4; ++r) {
              int pl = 16 * ii + quad * 4 + r;
              tf[pl * STRF + wc0 + 16 * j + l15] = acc[ii][j][r] + bs[j];
            }
      }
      __syncthreads();
      constexpr int CHUNKS = 64 * COUT / 4;
      size_t gbase = (((size_t)b * MMX + m) * NNX + h * 64) * COUT;
      for (int idx = tid; idx < CHUNKS; idx += 256) {
        int px = idx / (COUT / 4), cg = idx % (COUT / 4);
        float4 a4 = *(float4*)&tf[px * STRF + cg * 4];
        size_t gx = gbase + (size_t)px * COUT + cg * 4;
        float4 xv = *(float4*)(xio + gx);
        float4 rr = make_float4(a4.x + xv.x, a4.y + xv.y, a4.z + xv.z, a4.w + xv.w);
        *(float4*)(xio + gx) = rr;
        __hip_bfloat16 o0 = __float2bfloat16(rr.x), o1 = __float2bfloat16(rr.y);
        __hip_bfloat16 o2 = __float2bfloat16(rr.z), o3 = __float2bfloat16(rr.w);
        ushort4 ov = make_ushort4(*(unsigned short*)&o0, *(unsigned short*)&o1,
                                  *(unsigned short*)&o2, *(unsigned short*)&o3);
        *(ushort4*)(xb + gx) = ov;
      }
      __syncthreads();
    }
  }
}

// ---------------------------------------------------------------------------
// head split-K: P[ks][bm][t] = sum_{k in slice} Xb[bm][k] * hwT[t][k]
// ---------------------------------------------------------------------------
__global__ __launch_bounds__(256) void head_split(
    const __hip_bfloat16* __restrict__ xb,   // [nbm][8192]
    const __hip_bfloat16* __restrict__ hwT,  // [96][8192]
    float* __restrict__ P, int nbm) {        // [8][nbm][96]
  const int ks = blockIdx.x & 7;
  const int bm0 = (blockIdx.x >> 3) * 64;
  const int lane = threadIdx.x & 63;
  const int w = threadIdx.x >> 6;
  const int l15 = lane & 15;
  const int quad = lane >> 4;
  const int bmw = bm0 + w * 16;

  floatx4 acc[6];
#pragma unroll
  for (int j = 0; j < 6; ++j) acc[j] = (floatx4)0.f;

  const int k0 = ks * 1024;
  const __hip_bfloat16* abase = xb + (size_t)(bmw + l15) * 8192 + k0;
  const __hip_bfloat16* bbase = hwT + (size_t)l15 * 8192 + k0;
#pragma unroll 4
  for (int kc = 0; kc < 32; ++kc) {
    const int kb = kc * 32 + quad * 8;
    bfx8 a = *(const bfx8*)(abase + kb);
#pragma unroll
    for (int j = 0; j < 6; ++j) {
      bfx8 bv = *(const bfx8*)(bbase + (size_t)(16 * j) * 8192 + kb);
      acc[j] = __builtin_amdgcn_mfma_f32_16x16x32_bf16(a, bv, acc[j], 0, 0, 0);
    }
  }
#pragma unroll
  for (int j = 0; j < 6; ++j) {
    int t = 16 * j + l15;
#pragma unroll
    for (int r = 0; r < 4; ++r) {
      int bm = bmw + quad * 4 + r;
      P[((size_t)ks * nbm + bm) * TTX + t] = acc[j][r];
    }
  }
}

__global__ __launch_bounds__(256) void head_reduce(
    const float* __restrict__ P, const float* __restrict__ hb,
    float* __restrict__ out, int nbm, int bm_off) {
  int i = blockIdx.x * 256 + threadIdx.x;    // nbm*96
  int t = i % TTX;
  int bm = i / TTX;
  float s = hb[t];
#pragma unroll
  for (int ks = 0; ks < 8; ++ks) s += P[((size_t)ks * nbm + bm) * TTX + t];
  out[(size_t)(bm_off + bm) * TTX + t] = s;
}

// ---------------------------------------------------------------------------
extern "C" void kernel_launch(void* const* d_in, const int* in_sizes, int n_in,
                              void* d_out, int out_size, void* d_ws, size_t ws_size,
                              hipStream_t stream) {
  const float* x      = (const float*)d_in[0];
  const float* emb_w  = (const float*)d_in[1];
  const float* emb_b  = (const float*)d_in[2];
  const float* head_w = (const float*)d_in[3];
  const float* head_b = (const float*)d_in[4];
  const float* dw_w1  = (const float*)d_in[5];
  const float* dw_b1  = (const float*)d_in[6];
  const float* f11_w  = (const float*)d_in[7];
  const float* f11_b  = (const float*)d_in[8];
  const float* f12_w  = (const float*)d_in[9];
  const float* f12_b  = (const float*)d_in[10];
  const float* dw_w2  = (const float*)d_in[11];
  const float* dw_b2  = (const float*)d_in[12];
  const float* f21_w  = (const float*)d_in[13];
  const float* f21_b  = (const float*)d_in[14];
  const float* f22_w  = (const float*)d_in[15];
  const float* f22_b  = (const float*)d_in[16];

  // fixed: 4 conv wT (98304 bf16 each) + hwT (786432 bf16)
  const size_t WEL = 98304, HWEL = 786432;
  __hip_bfloat16* wt11 = (__hip_bfloat16*)d_ws;
  __hip_bfloat16* wt12 = wt11 + WEL;
  __hip_bfloat16* wt21 = wt12 + WEL;
  __hip_bfloat16* wt22 = wt21 + WEL;
  __hip_bfloat16* hwT  = wt22 + WEL;
  char* dyn = (char*)(hwT + HWEL);
  const size_t fixed_bytes = (4 * WEL + HWEL) * 2;

  const size_t YP_B = (size_t)PROWS * PCOLS * DDX * 2;    // 1,114,880
  const size_t HP_B = (size_t)PROWS * PCOLS * RDX * 2;    // 2,229,760
  const size_t X_B  = (size_t)MMX * NNX * DDX * 4;        // 2,097,152
  const size_t XB_B = (size_t)MMX * NNX * DDX * 2;        // 1,048,576
  const size_t P_B  = (size_t)8 * MMX * TTX * 4;          //   196,608
  const size_t PER_B = YP_B + HP_B + X_B + XB_B + P_B;
  int Bc = 32;
  while (Bc > 1 && fixed_bytes + (size_t)Bc * PER_B > ws_size) Bc >>= 1;

  __hip_bfloat16* Yp = (__hip_bfloat16*)dyn;
  __hip_bfloat16* Hp = (__hip_bfloat16*)(dyn + (size_t)Bc * YP_B);
  float* X  = (float*)(dyn + (size_t)Bc * (YP_B + HP_B));
  __hip_bfloat16* Xb = (__hip_bfloat16*)(dyn + (size_t)Bc * (YP_B + HP_B + X_B));
  float* P  = (float*)(dyn + (size_t)Bc * (YP_B + HP_B + X_B + XB_B));
  const int nbm = Bc * MMX;

  // prep (once per launch)
  castw_kernel<<<384, 256, 0, stream>>>(f11_w, wt11, RDX, DDX);
  castw_kernel<<<384, 256, 0, stream>>>(f12_w, wt12, DDX, RDX);
  castw_kernel<<<384, 256, 0, stream>>>(f21_w, wt21, RDX, DDX);
  castw_kernel<<<384, 256, 0, stream>>>(f22_w, wt22, DDX, RDX);
  headw_kernel<<<3072, 256, 0, stream>>>(head_w, hwT);
  // zero pad frames only (interiors always rewritten before read)
  halo_zero<<<(32 * 518 * DDX + 255) / 256, 256, 0, stream>>>(Yp, DDX);
  halo_zero<<<(32 * 518 * RDX + 255) / 256, 256, 0, stream>>>(Hp, RDX);

  for (int b0 = 0; b0 < 32; b0 += Bc) {
    int bm_off = b0 * MMX;
    embed_kernel<<<Bc * 2048, 256, 0, stream>>>(x, emb_w, emb_b, X, bm_off);

    for (int l = 0; l < 2; ++l) {
      const float* dwW = l ? dw_w2 : dw_w1;
      const float* dwB = l ? dw_b2 : dw_b1;
      const __hip_bfloat16* w1 = l ? wt21 : wt11;
      const float* b1 = l ? f21_b : f11_b;
      const __hip_bfloat16* w2 = l ? wt22 : wt12;
      const float* b2 = l ? f22_b : f12_b;

      dw_kernel<<<Bc * 2048, 256, 0, stream>>>(X, dwW, dwB, Yp);
      conv_pipe<DDX, RDX, true>
          <<<Bc * MMX, 256, 0, stream>>>(Yp, w1, b1, Hp, nullptr, nullptr);
      conv_pipe<RDX, DDX, false>
          <<<Bc * MMX, 256, 0, stream>>>(Hp, w2, b2, nullptr, X, Xb);
    }

    head_split<<<Bc * 8, 256, 0, stream>>>(Xb, hwT, P, nbm);
    head_reduce<<<Bc * 24, 256, 0, stream>>>(P, head_b, (float*)d_out, nbm, bm_off);
  }
}